// Round 15
// baseline (171.061 us; speedup 1.0000x reference)
//
#include <hip/hip_runtime.h>
#include <hip/hip_bf16.h>

// LinearShift forward:
//   out = q16(input) @ (exp2(round(shift))*sign(sign)).T + q16(bias)
// R15: B NEVER TOUCHES LDS. Convert pre-packs Wq in MFMA-fragment order
// [col/16][k/32][lane][8bf16]; GEMM loads B fragments straight from global,
// perfectly coalesced (64 lanes x 16B = 1KB/inst), L2/L3-resident.
//  - LDS port traffic per K-tile: reads 192->128KB, writes 128->64KB (-38%)
//    -> attacks the measured LDS-port bound (m134: ~85B/cyc b128 reads)
//  - LDS 64KB: buf{0,1} x {A0,A1} x 8192 bf16; A staging/swizzle as R13
//    (3-bit XOR, 0 conflicts; inverse-swizzled global_load_lds w=16)
//  - B reg double-buffer via reload-after-last-use: b1f(t) at ph0 (prev use
//    prev-ph3), b0f(t+1) at ph3 (prev use ph2) -- no extra register sets
//  - sync: mid BARF (end-ph1) + boundary VMW(6)+BARF per K-tile
//    (in-order vm queue: [A1(t+1)^2, {b0f^4, A0(t+2)^2}] -> VMW(6) drains
//    exactly A1; A0(t+2) drained by t+1's compiler b1f-wait, in-order)
//  - no lgkm pins; setprio around MFMA; bijective XCD swizzle

#define BM 256
#define BN 256
#define BK 64

typedef __bf16 bf16_t;
typedef __attribute__((ext_vector_type(8))) __bf16 bf16x8;
typedef __attribute__((ext_vector_type(4))) __bf16 bf16x4;
typedef __attribute__((ext_vector_type(4))) float f32x4;

__device__ __forceinline__ float q16(float x) {
    // floor-quantize to 2^-16 steps, clamp to [-2^15, 2^15 - 1]
    float f = floorf(x * 65536.0f) * (1.0f / 65536.0f);
    return fminf(fmaxf(f, -32768.0f), 32767.0f);
}

// part 1: input -> Aq (row-major bf16)
// part 2: (shift,sign) -> Wq in B-FRAGMENT order: idx -> lane=idx&63,
//   kb=(idx>>6)%(K/32), g=(idx>>6)/(K/32); col=g*16+(lane&15),
//   k0=kb*32+(lane>>4)*8; Wq[idx*8 .. +7] = w(col, k0..k0+7)
__global__ void convert_kernel(const float* __restrict__ in,
                               const float* __restrict__ shift,
                               const float* __restrict__ sign_,
                               bf16_t* __restrict__ aq,
                               bf16_t* __restrict__ wq,
                               int nvecA, int nfragW, int K) {
    const int stride = gridDim.x * blockDim.x;
    const int t0 = blockIdx.x * blockDim.x + threadIdx.x;
    for (int i = t0; i < nvecA; i += stride) {
        float4 v = reinterpret_cast<const float4*>(in)[i];
        bf16x4 oa;
        oa[0] = (bf16_t)q16(v.x);
        oa[1] = (bf16_t)q16(v.y);
        oa[2] = (bf16_t)q16(v.z);
        oa[3] = (bf16_t)q16(v.w);
        reinterpret_cast<bf16x4*>(aq)[i] = oa;
    }
    const int kbN = K >> 5;
    for (int i = t0; i < nfragW; i += stride) {
        const int lane = i & 63;
        const int tmp = i >> 6;
        const int kb = tmp % kbN;
        const int g = tmp / kbN;
        const int col = (g << 4) + (lane & 15);
        const int k0 = kb * 32 + (lane >> 4) * 8;
        const size_t off = (size_t)col * K + k0;
        float4 sh0 = *reinterpret_cast<const float4*>(shift + off);
        float4 sh1 = *reinterpret_cast<const float4*>(shift + off + 4);
        float4 sg0 = *reinterpret_cast<const float4*>(sign_ + off);
        float4 sg1 = *reinterpret_cast<const float4*>(sign_ + off + 4);
        float shs[8] = {sh0.x, sh0.y, sh0.z, sh0.w, sh1.x, sh1.y, sh1.z, sh1.w};
        float sgs[8] = {sg0.x, sg0.y, sg0.z, sg0.w, sg1.x, sg1.y, sg1.z, sg1.w};
        bf16x8 ow;
#pragma unroll
        for (int j = 0; j < 8; ++j) {
            float s = fminf(fmaxf(sgs[j], -1.0f), 1.0f);
            float sv = (s > 0.0f) ? 1.0f : ((s < 0.0f) ? -1.0f : 0.0f);
            ow[j] = (bf16_t)(exp2f(rintf(shs[j])) * sv);
        }
        reinterpret_cast<bf16x8*>(wq)[i] = ow;
    }
}

// ---- 256x256 bf16 GEMM: C = A*B^T + q16(bias); B from fragment-packed Wq

#define VMW(N) asm volatile("s_waitcnt vmcnt(" #N ")" ::: "memory")
#define BARF() do { __builtin_amdgcn_s_barrier(); asm volatile("" ::: "memory"); } while (0)

// stage one A half-tile (128 rows x 64 cols, 2 x global_load_lds w=16)
#define STAGE(LDSOFF, SRC) do {                                                          \
    const bf16_t* _s = (SRC);                                                            \
    bf16_t* _d = &lds[(LDSOFF)] + tid * 8;                                               \
    __builtin_amdgcn_global_load_lds((const __attribute__((address_space(1))) void*)_s,  \
                                     (__attribute__((address_space(3))) void*)_d,        \
                                     16, 0, 0);                                          \
    __builtin_amdgcn_global_load_lds(                                                    \
        (const __attribute__((address_space(1))) void*)(_s + (size_t)64 * K),            \
        (__attribute__((address_space(3))) void*)(_d + 4096), 16, 0, 0);                 \
} while (0)

// read A fragments for row-half MH (8 x ds_read_b128, swizzled); wave's slot=wm
#define READ_A(BUF, MH) do {                                                             \
    const bf16_t* _As = &lds[(BUF) * 16384 + wm * 8192];                                 \
    _Pragma("unroll") for (int m = 0; m < 4; ++m)                                        \
        _Pragma("unroll") for (int kk = 0; kk < 2; ++kk)                                 \
            af[m][kk] = *(const bf16x8*)&_As[((MH) * 64 + m * 16 + fr) * 64 +            \
                                             ((((kk << 2) | hi) ^ fr7) << 3)];           \
} while (0)

// load B fragments straight from fragment-packed Wq (coalesced 1KB/inst)
#define LOADB0(T) do {                                                                   \
    _Pragma("unroll") for (int n = 0; n < 2; ++n)                                        \
        _Pragma("unroll") for (int kk = 0; kk < 2; ++kk)                                 \
            b0f[n][kk] = *(const bf16x8*)(gB[n] + ((size_t)(T) * 2 + kk) * 512);         \
} while (0)
#define LOADB1(T) do {                                                                   \
    _Pragma("unroll") for (int n = 0; n < 2; ++n)                                        \
        _Pragma("unroll") for (int kk = 0; kk < 2; ++kk)                                 \
            b1f[n][kk] = *(const bf16x8*)(gB[n + 2] + ((size_t)(T) * 2 + kk) * 512);     \
} while (0)

// 16 MFMA = one C-quadrant x K=64
#define QUAD(MH, NH, BF) do {                                                            \
    _Pragma("unroll") for (int m = 0; m < 4; ++m)                                        \
        _Pragma("unroll") for (int n = 0; n < 2; ++n)                                    \
            _Pragma("unroll") for (int kk = 0; kk < 2; ++kk)                             \
                acc[(MH) * 4 + m][(NH) * 2 + n] =                                        \
                    __builtin_amdgcn_mfma_f32_16x16x32_bf16(                             \
                        af[m][kk], BF[n][kk], acc[(MH) * 4 + m][(NH) * 2 + n], 0, 0, 0); \
} while (0)

#define MFMA_PH(MH, NH, BF)                                                              \
    __builtin_amdgcn_s_setprio(1);                                                       \
    QUAD(MH, NH, BF);                                                                    \
    __builtin_amdgcn_s_setprio(0);

// One K-tile = 4 phases; quadrants (0,0),(0,1),(1,0),(1,1).
// ph0: load b1f(t) [before A1 stage: keeps A1 in flight past compiler's ph1
//      b1f-wait]; stage A1(t+1)->buf^1 [slot last read t-1 ph2, boundary-
//      barrier-separated]; read af0; MFMA(0,0) on b0f (loaded prev ph3).
// ph1: MFMA(0,1) on b1f.  BARF (mid WAR fence).
// ph2: read af1; MFMA(1,0) on b0f (regs free after).
// ph3: load b0f(t+1); stage A0(t+2)->buf [af0-slot rows 64-127 read at ph2:
//      write lands ~900cyc after ph3 issue, reads complete ~400cyc after the
//      synchronized mid-barrier release -- same latency margin as R13];
//      MFMA(1,1) on b1f; VMW(6) [queue: A1(t+1)^2 then {b0f^4,A0^2} -> drains
//      exactly A1(t+1)]; BARF.
#define TILE(BUF, T, S1, SB0, SA0, ENDW) do {                                            \
    /* phase 0 */                                                                        \
    LOADB1(T);                                                                           \
    if (S1) STAGE(((BUF) ^ 1) * 16384 + 8192, srcA1 + (size_t)((T) + 1) * 64);           \
    READ_A(BUF, 0);                                                                      \
    MFMA_PH(0, 0, b0f)                                                                   \
    /* phase 1 */                                                                        \
    MFMA_PH(0, 1, b1f)                                                                   \
    BARF();                                                                              \
    /* phase 2 */                                                                        \
    READ_A(BUF, 1);                                                                      \
    MFMA_PH(1, 0, b0f)                                                                   \
    /* phase 3 */                                                                        \
    if (SB0) LOADB0((T) + 1);                                                            \
    if (SA0) STAGE((BUF) * 16384 + 0, srcA0 + (size_t)((T) + 2) * 64);                   \
    MFMA_PH(1, 1, b1f)                                                                   \
    if ((ENDW) == 6) VMW(6);                                                             \
    else if ((ENDW) == 4) VMW(4);                                                        \
    else if ((ENDW) == 0) VMW(0);                                                        \
    BARF();                                                                              \
} while (0)

__global__ __launch_bounds__(512, 2)
void gemm256_kernel(const bf16_t* __restrict__ A,
                    const bf16_t* __restrict__ Wq,
                    const float* __restrict__ bias,
                    float* __restrict__ C,
                    int M, int N, int K) {
    // 64 KiB: buf{0,1} x {A0,A1} x 8192 bf16 (128 rows x 64 cols each)
    __shared__ bf16_t lds[32768];

    const int ntn = N / BN;
    const int nwg = gridDim.x;
    // bijective XCD swizzle (8 XCDs)
    const int q = nwg >> 3, r = nwg & 7;
    const int xcd = blockIdx.x & 7, lid = blockIdx.x >> 3;
    const int swz = (xcd < r ? xcd * (q + 1) : r * (q + 1) + (xcd - r) * q) + lid;
    const int tile_m = (swz / ntn) * BM;
    const int tile_n = (swz % ntn) * BN;

    const int tid = threadIdx.x;
    const int lane = tid & 63;
    const int wid = tid >> 6;
    const int wm = wid >> 2;   // 0..1: row half (A slot)
    const int wn = wid & 3;    // 0..3: col quarter
    const int fr = lane & 15;
    const int hi = lane >> 4;
    const int fr7 = fr & 7;

    // A staging source (inverse-swizzled column; bytes 4-6 ^= row bits 0-2)
    const int colsrc_e = ((((tid & 7) * 16) ^ ((tid & 56) << 1)) >> 1);
    const bf16_t* srcA0 = A + (size_t)(tile_m + (tid >> 3)) * K + colsrc_e;
    const bf16_t* srcA1 = srcA0 + (size_t)128 * K;

    // B fragment bases: col-group r of this wave = tile_n/16 + wn*4 + r
    const int kbN = K >> 5;
    const bf16_t* gB[4];
#pragma unroll
    for (int rr = 0; rr < 4; ++rr)
        gB[rr] = Wq + ((size_t)(tile_n / 16 + wn * 4 + rr) * kbN * 64 + lane) * 8;

    bf16x8 af[4][2], b0f[2][2], b1f[2][2];
    f32x4 acc[8][4] = {};

    // prologue: A0(0), A1(0), A0(1) staged; b0f(0) loaded.
    // VMW(6): queue [A0(0)^2, A1(0)^2, A0(1)^2, b0f^4] -> drains tile0's A.
    STAGE(0, srcA0);                   // buf0.A0 t0
    STAGE(8192, srcA1);                // buf0.A1 t0
    STAGE(16384 + 0, srcA0 + 64);      // buf1.A0 t1
    LOADB0(0);
    VMW(6);
    BARF();

    const int npairs = K / 128;        // 2 K-tiles per iteration
    for (int i = 0; i < npairs - 1; ++i) {
        TILE(0, 2 * i, 1, 1, 1, 6);
        TILE(1, 2 * i + 1, 1, 1, 1, 6);
    }
    // t=62: stage A1(63) at ph0; load b0f(63); no A0(64).
    //   boundary queue [A1(63)^2, b0f(63)^4] -> VMW(4) drains A1(63).
    TILE(0, 2 * npairs - 2, 1, 1, 0, 4);
    // t=63: b1f(63) at ph0 only; nothing else; no waits needed at end.
    TILE(1, 2 * npairs - 1, 0, 0, 0, -1);

    // epilogue: C/D layout col=lane&15, row=(lane>>4)*4+reg
    float qb[4];
#pragma unroll
    for (int ng = 0; ng < 4; ++ng)
        qb[ng] = q16(bias[tile_n + wn * 64 + ng * 16 + fr]);
#pragma unroll
    for (int mg = 0; mg < 8; ++mg) {
        const int grow0 = tile_m + wm * 128 + mg * 16 + hi * 4;
#pragma unroll
        for (int ng = 0; ng < 4; ++ng) {
            const int gcol = tile_n + wn * 64 + ng * 16 + fr;
#pragma unroll
            for (int rr = 0; rr < 4; ++rr)
                C[(size_t)(grow0 + rr) * N + gcol] = acc[mg][ng][rr] + qb[ng];
        }
    }
}

extern "C" void kernel_launch(void* const* d_in, const int* in_sizes, int n_in,
                              void* d_out, int out_size, void* d_ws, size_t ws_size,
                              hipStream_t stream) {
    const float* inp   = (const float*)d_in[0];
    const float* shift = (const float*)d_in[1];
    const float* sign_ = (const float*)d_in[2];
    const float* bias  = (const float*)d_in[3];
    float* out = (float*)d_out;

    const int OUT_F = in_sizes[3];              // 4096
    const int IN_F  = in_sizes[1] / OUT_F;      // 4096
    const int Mrows = in_sizes[0] / IN_F;       // 4096

    bf16_t* Aq = (bf16_t*)d_ws;
    bf16_t* Wq = Aq + (size_t)Mrows * IN_F;     // (M*K + N*K)*2 = 67.2 MB of ws

    const int nA = Mrows * IN_F;
    const int nW = OUT_F * IN_F;

    convert_kernel<<<2048, 256, 0, stream>>>(inp, shift, sign_, Aq, Wq,
                                             nA >> 2, nW >> 3, IN_F);

    dim3 grid((Mrows / BM) * (OUT_F / BN));
    gemm256_kernel<<<grid, 512, 0, stream>>>(Aq, Wq, bias, out,
                                             Mrows, OUT_F, IN_F);
}

// Round 16
// 162.195 us; speedup vs baseline: 1.0547x; 1.0547x over previous
//
#include <hip/hip_runtime.h>
#include <hip/hip_bf16.h>

// LinearShift forward:
//   out = q16(input) @ (exp2(round(shift))*sign(sign)).T + q16(bias)
// R16: 4-DEEP RING, BK=32, barrier-free tile body.
//  - BM=BN=256, 8 waves (2Mx4N), per-wave 128x64; 32 MFMA 16x16x32 per tile
//  - LDS: 4 ring buffers x 32KB (A 16KB + B 16KB) = 128KB
//  - tile t: read ring[t%4]; stage t+3 into ring[(t+3)%4] (= buffer finished
//    by tile t-1, BEHIND the last barrier -> WAR safe by barrier separation);
//    reads hit data staged 3 tiles (~5000cyc) earlier -> RAW trivially safe
//  - sync: ONE barrier + ONE counted VMW(8) per tile (drains exactly t+1's 4
//    loads, issued 2 tiles earlier); no mid barriers, no lgkm pins ->
//    12 ds_reads + 32 MFMAs form one block the compiler pipelines freely
//  - LDS layout: R12's row-paired [128 pr][128B] XOR swizzle -- the proven
//    0-conflict geometry for 32k rows (slot=((r&1)*4+kq)^((r>>1)&3));
//    same proven staging inverse (global_load_lds w=16, linear dest)
//  - s_setprio around MFMA cluster; bijective XCD blockIdx swizzle
// Convert kernel: R13's fused version (memory-roofline).

#define BM 256
#define BN 256

typedef __bf16 bf16_t;
typedef __attribute__((ext_vector_type(8))) __bf16 bf16x8;
typedef __attribute__((ext_vector_type(4))) __bf16 bf16x4;
typedef __attribute__((ext_vector_type(4))) float f32x4;

__device__ __forceinline__ float q16(float x) {
    // floor-quantize to 2^-16 steps, clamp to [-2^15, 2^15 - 1]
    float f = floorf(x * 65536.0f) * (1.0f / 65536.0f);
    return fminf(fmaxf(f, -32768.0f), 32767.0f);
}

// fused: element i of input -> Aq; element i of (shift,sign) -> Wq (nA == nW)
__global__ void convert_kernel(const float* __restrict__ in,
                               const float* __restrict__ shift,
                               const float* __restrict__ sign_,
                               bf16_t* __restrict__ aq,
                               bf16_t* __restrict__ wq, int nvec) {
    int stride = gridDim.x * blockDim.x;
    for (int i = blockIdx.x * blockDim.x + threadIdx.x; i < nvec; i += stride) {
        float4 v = reinterpret_cast<const float4*>(in)[i];
        bf16x4 oa;
        oa[0] = (bf16_t)q16(v.x);
        oa[1] = (bf16_t)q16(v.y);
        oa[2] = (bf16_t)q16(v.z);
        oa[3] = (bf16_t)q16(v.w);
        reinterpret_cast<bf16x4*>(aq)[i] = oa;

        float4 sh = reinterpret_cast<const float4*>(shift)[i];
        float4 sg = reinterpret_cast<const float4*>(sign_)[i];
        float shs[4] = {sh.x, sh.y, sh.z, sh.w};
        float sgs[4] = {sg.x, sg.y, sg.z, sg.w};
        bf16x4 ow;
#pragma unroll
        for (int j = 0; j < 4; ++j) {
            float s = fminf(fmaxf(sgs[j], -1.0f), 1.0f);
            float sv = (s > 0.0f) ? 1.0f : ((s < 0.0f) ? -1.0f : 0.0f);
            ow[j] = (bf16_t)(exp2f(rintf(shs[j])) * sv);
        }
        reinterpret_cast<bf16x4*>(wq)[i] = ow;
    }
}

// ---- 256x256 bf16 GEMM, BK=32: C[M][N] = A[M][K]*B[N][K]^T + q16(bias)[N]

#define VMW(N) asm volatile("s_waitcnt vmcnt(" #N ")" ::: "memory")
#define BARF() do { __builtin_amdgcn_s_barrier(); asm volatile("" ::: "memory"); } while (0)

#define GLDS(SRC, DST)                                                                   \
    __builtin_amdgcn_global_load_lds(                                                    \
        (const __attribute__((address_space(1))) void*)(SRC),                            \
        (__attribute__((address_space(3))) void*)(DST), 16, 0, 0)

// stage K-tile T into ring buffer base RB (elements): A 16KB + B 16KB,
// 4 x global_load_lds w=16 per thread (each issue = 512thr x 16B = 8KB = 128 rows)
#define STAGE_TILE(RB, T) do {                                                           \
    GLDS(srcA + (size_t)(T) * 32,                 &lds[(RB)] + tid * 8);                 \
    GLDS(srcA + (size_t)128 * K + (size_t)(T) * 32, &lds[(RB) + 4096] + tid * 8);        \
    GLDS(srcB + (size_t)(T) * 32,                 &lds[(RB) + 8192] + tid * 8);          \
    GLDS(srcB + (size_t)128 * K + (size_t)(T) * 32, &lds[(RB) + 12288] + tid * 8);       \
} while (0)

// 12 x ds_read_b128: A 8 frags (rows wm*128+m*16+fr) + B 4 frags (cols
// wn*64+n*16+fr) from the row-paired swizzled layout
#define READ_FRAGS(RB) do {                                                              \
    _Pragma("unroll") for (int m = 0; m < 8; ++m)                                        \
        af[m] = *(const bf16x8*)&lds[(RB) + (wm * 64 + m * 8 + prw) * 64 + sl8];         \
    _Pragma("unroll") for (int n = 0; n < 4; ++n)                                        \
        bf[n] = *(const bf16x8*)&lds[(RB) + 8192 + (wn * 32 + n * 8 + prw) * 64 + sl8];  \
} while (0)

// 32 MFMA = whole 128x64 wave-tile x K=32
#define MFMA32() do {                                                                    \
    __builtin_amdgcn_s_setprio(1);                                                       \
    _Pragma("unroll") for (int m = 0; m < 8; ++m)                                        \
        _Pragma("unroll") for (int n = 0; n < 4; ++n)                                    \
            acc[m][n] = __builtin_amdgcn_mfma_f32_16x16x32_bf16(                         \
                af[m], bf[n], acc[m][n], 0, 0, 0);                                       \
    __builtin_amdgcn_s_setprio(0);                                                       \
} while (0)

// one K-tile; SB = ring slot (t+3)%4 in element offset
#define TILE(RB, T, DOS, W, DOBAR) do {                                                  \
    READ_FRAGS(RB);                                                                      \
    if (DOS) STAGE_TILE((((RB) + 49152) % 65536), (T) + 3);                              \
    MFMA32();                                                                            \
    if ((W) == 8) VMW(8);                                                                \
    else if ((W) == 4) VMW(4);                                                           \
    else if ((W) == 0) VMW(0);                                                           \
    if (DOBAR) BARF();                                                                   \
} while (0)

__global__ __launch_bounds__(512, 2)
void gemm256_kernel(const bf16_t* __restrict__ A,
                    const bf16_t* __restrict__ B,
                    const float* __restrict__ bias,
                    float* __restrict__ C,
                    int M, int N, int K) {
    // 128 KiB: 4 ring buffers x 16384 bf16 (A [128pr][64e] | B [128pr][64e])
    __shared__ bf16_t lds[65536];

    const int ntn = N / BN;
    const int nwg = gridDim.x;
    // bijective XCD swizzle (8 XCDs)
    const int q = nwg >> 3, r = nwg & 7;
    const int xcd = blockIdx.x & 7, lid = blockIdx.x >> 3;
    const int swz = (xcd < r ? xcd * (q + 1) : r * (q + 1) + (xcd - r) * q) + lid;
    const int tile_m = (swz / ntn) * BM;
    const int tile_n = (swz % ntn) * BN;

    const int tid = threadIdx.x;
    const int lane = tid & 63;
    const int wid = tid >> 6;
    const int wm = wid >> 2;   // 0..1: row half (128 rows)
    const int wn = wid & 3;    // 0..3: col quarter (64 cols)
    const int fr = lane & 15;
    const int hi = lane >> 4;  // 0..3: k-quarter (k0 = hi*8)
    const int prw = fr >> 1;
    // slot = ((r&1)*4 + kq) ^ ((r>>1)&3): 8 slots x 2 lanes per 16-lane group,
    // distinct 128B pair-rows -> conflict-free (R12 measured 0)
    const int sl8 = ((((fr & 1) << 2) | hi) ^ ((fr >> 1) & 3)) << 3;

    // staging source (proven R12 inverse): thread t -> pair-row t>>3 (+64/issue),
    // slot t&7 -> raw=(t&7)^((t>>3)&3) -> row=2*(t>>3)+(raw>>2), kchunk=raw&3
    const int sraw = (tid & 7) ^ ((tid >> 3) & 3);
    const int rloc = 2 * (tid >> 3) + (sraw >> 2);
    const int kloc = (sraw & 3) << 3;
    const bf16_t* srcA = A + (size_t)(tile_m + rloc) * K + kloc;
    const bf16_t* srcB = B + (size_t)(tile_n + rloc) * K + kloc;

    bf16x8 af[8], bf[4];
    f32x4 acc[8][4] = {};

    // prologue: stage t0,t1,t2; VMW(8) drains t0 (t1,t2 in flight = 8)
    STAGE_TILE(0, 0);
    STAGE_TILE(16384, 1);
    STAGE_TILE(32768, 2);
    VMW(8);
    BARF();

    // 128 K-tiles (K=4096, BK=32); main loop t=0..123 (stages t+3 <= 126)
    for (int i = 0; i < 31; ++i) {
        TILE(0,     4 * i,     1, 8, 1);
        TILE(16384, 4 * i + 1, 1, 8, 1);
        TILE(32768, 4 * i + 2, 1, 8, 1);
        TILE(49152, 4 * i + 3, 1, 8, 1);
    }
    TILE(0,     124, 1, 8, 1);   // stages t=127; drains t=125
    TILE(16384, 125, 0, 4, 1);   // drains t=126
    TILE(32768, 126, 0, 0, 1);   // drains t=127
    TILE(49152, 127, 0, -1, 0);  // no waits, no barrier

    // epilogue: C/D layout col=lane&15, row=(lane>>4)*4+reg
    float qb[4];
#pragma unroll
    for (int n = 0; n < 4; ++n)
        qb[n] = q16(bias[tile_n + wn * 64 + n * 16 + fr]);
#pragma unroll
    for (int m = 0; m < 8; ++m) {
        const int grow0 = tile_m + wm * 128 + m * 16 + hi * 4;
#pragma unroll
        for (int n = 0; n < 4; ++n) {
            const int gcol = tile_n + wn * 64 + n * 16 + fr;
#pragma unroll
            for (int rr = 0; rr < 4; ++rr)
                C[(size_t)(grow0 + rr) * N + gcol] = acc[m][n][rr] + qb[n];
        }
    }
}

extern "C" void kernel_launch(void* const* d_in, const int* in_sizes, int n_in,
                              void* d_out, int out_size, void* d_ws, size_t ws_size,
                              hipStream_t stream) {
    const float* inp   = (const float*)d_in[0];
    const float* shift = (const float*)d_in[1];
    const float* sign_ = (const float*)d_in[2];
    const float* bias  = (const float*)d_in[3];
    float* out = (float*)d_out;

    const int OUT_F = in_sizes[3];              // 4096
    const int IN_F  = in_sizes[1] / OUT_F;      // 4096
    const int Mrows = in_sizes[0] / IN_F;       // 4096

    bf16_t* Aq = (bf16_t*)d_ws;
    bf16_t* Wq = Aq + (size_t)Mrows * IN_F;     // (M*K + N*K)*2 = 67.2 MB of ws

    const int nA = Mrows * IN_F;                // == OUT_F * IN_F here

    convert_kernel<<<2048, 256, 0, stream>>>(inp, shift, sign_, Aq, Wq, nA >> 2);

    dim3 grid((Mrows / BM) * (OUT_F / BN));
    gemm256_kernel<<<grid, 512, 0, stream>>>(Aq, Wq, bias, out,
                                             Mrows, OUT_F, IN_F);
}

// Round 17
// 155.299 us; speedup vs baseline: 1.1015x; 1.0444x over previous
//
#include <hip/hip_runtime.h>
#include <hip/hip_bf16.h>

// LinearShift forward:
//   out = q16(input) @ (exp2(round(shift))*sign(sign)).T + q16(bias)
// R17 (final consolidation) = R9 GEMM skeleton (empirical best, 113.4us)
//   + fused convert kernel (R13)  + setprio REMOVED (T5/m190: setprio is
//   null-to-negative on lockstep GEMM structures; never isolated here).
// GEMM: 256x256 tile, BK=64, 16x16x32 MFMA, 8 waves (2Mx4N), 128KiB LDS
// double-buffered half-tiles, global_load_lds w=16 + inverse-swizzled source,
// 3-bit XOR read swizzle (0 conflicts, R2 PMC), 2 barriers/K-tile (end-ph1
// WAR fence + end-ph3 boundary), single counted vmcnt(4)/tile, no lgkm pins
// (compiler emits per-use lgkmcnt), bijective XCD blockIdx swizzle.
// Session plateau: 10 structural variants all land 113-116us GEMM
// (~1215 TF, 49% dense peak); conversions at 5.9 TB/s HBM roofline.

#define BM 256
#define BN 256
#define BK 64

typedef __bf16 bf16_t;
typedef __attribute__((ext_vector_type(8))) __bf16 bf16x8;
typedef __attribute__((ext_vector_type(4))) __bf16 bf16x4;
typedef __attribute__((ext_vector_type(4))) float f32x4;

__device__ __forceinline__ float q16(float x) {
    // floor-quantize to 2^-16 steps, clamp to [-2^15, 2^15 - 1]
    float f = floorf(x * 65536.0f) * (1.0f / 65536.0f);
    return fminf(fmaxf(f, -32768.0f), 32767.0f);
}

// fused: element i of input -> Aq; element i of (shift,sign) -> Wq (nA == nW)
__global__ void convert_kernel(const float* __restrict__ in,
                               const float* __restrict__ shift,
                               const float* __restrict__ sign_,
                               bf16_t* __restrict__ aq,
                               bf16_t* __restrict__ wq, int nvec) {
    int stride = gridDim.x * blockDim.x;
    for (int i = blockIdx.x * blockDim.x + threadIdx.x; i < nvec; i += stride) {
        float4 v = reinterpret_cast<const float4*>(in)[i];
        bf16x4 oa;
        oa[0] = (bf16_t)q16(v.x);
        oa[1] = (bf16_t)q16(v.y);
        oa[2] = (bf16_t)q16(v.z);
        oa[3] = (bf16_t)q16(v.w);
        reinterpret_cast<bf16x4*>(aq)[i] = oa;

        float4 sh = reinterpret_cast<const float4*>(shift)[i];
        float4 sg = reinterpret_cast<const float4*>(sign_)[i];
        float shs[4] = {sh.x, sh.y, sh.z, sh.w};
        float sgs[4] = {sg.x, sg.y, sg.z, sg.w};
        bf16x4 ow;
#pragma unroll
        for (int j = 0; j < 4; ++j) {
            float s = fminf(fmaxf(sgs[j], -1.0f), 1.0f);
            float sv = (s > 0.0f) ? 1.0f : ((s < 0.0f) ? -1.0f : 0.0f);
            ow[j] = (bf16_t)(exp2f(rintf(shs[j])) * sv);
        }
        reinterpret_cast<bf16x4*>(wq)[i] = ow;
    }
}

// ---- 256x256 8-phase bf16 GEMM: C[M][N] = A[M][K]*B[N][K]^T + q16(bias)[N]

#define VMW(N) asm volatile("s_waitcnt vmcnt(" #N ")" ::: "memory")
// raw barrier + zero-cost compiler memory fence
#define BARF() do { __builtin_amdgcn_s_barrier(); asm volatile("" ::: "memory"); } while (0)

// stage one half-tile (128 rows x 64 cols, 2 x global_load_lds w=16 per thread)
#define STAGE(LDSOFF, SRC) do {                                                          \
    const bf16_t* _s = (SRC);                                                            \
    bf16_t* _d = &lds[(LDSOFF)] + tid * 8;                                               \
    __builtin_amdgcn_global_load_lds((const __attribute__((address_space(1))) void*)_s,  \
                                     (__attribute__((address_space(3))) void*)_d,        \
                                     16, 0, 0);                                          \
    __builtin_amdgcn_global_load_lds(                                                    \
        (const __attribute__((address_space(1))) void*)(_s + (size_t)64 * K),            \
        (__attribute__((address_space(3))) void*)(_d + 4096), 16, 0, 0);                 \
} while (0)

// read A fragments for row-half MH (8 x ds_read_b128, swizzled)
#define READ_A(BUF, MH) do {                                                             \
    const bf16_t* _As = &lds[(BUF) * 32768 + wm * 8192];                                 \
    _Pragma("unroll") for (int m = 0; m < 4; ++m)                                        \
        _Pragma("unroll") for (int kk = 0; kk < 2; ++kk)                                 \
            af[m][kk] = *(const bf16x8*)&_As[((MH) * 64 + m * 16 + fr) * 64 +            \
                                             ((((kk << 2) | hi) ^ fr7) << 3)];           \
} while (0)

// read B fragments for col-half NH (4 x ds_read_b128, swizzled)
#define READ_B(BUF, NH, BF) do {                                                         \
    const bf16_t* _Bs = &lds[(BUF) * 32768 + 16384 + (wn >> 1) * 8192];                  \
    _Pragma("unroll") for (int n = 0; n < 2; ++n)                                        \
        _Pragma("unroll") for (int kk = 0; kk < 2; ++kk)                                 \
            BF[n][kk] = *(const bf16x8*)&_Bs[((wn & 1) * 64 + ((NH) * 2 + n) * 16 + fr)  \
                                                 * 64 +                                  \
                                             ((((kk << 2) | hi) ^ fr7) << 3)];           \
} while (0)

// 16 MFMA = one C-quadrant x K=64 (no setprio: T5/m190 harmful on lockstep)
#define QUAD(MH, NH, BF) do {                                                            \
    _Pragma("unroll") for (int m = 0; m < 4; ++m)                                        \
        _Pragma("unroll") for (int n = 0; n < 2; ++n)                                    \
            _Pragma("unroll") for (int kk = 0; kk < 2; ++kk)                             \
                acc[(MH) * 4 + m][(NH) * 2 + n] =                                        \
                    __builtin_amdgcn_mfma_f32_16x16x32_bf16(                             \
                        af[m][kk], BF[n][kk], acc[(MH) * 4 + m][(NH) * 2 + n], 0, 0, 0); \
} while (0)

// One K-tile = 4 phases; quadrant order (0,0),(0,1),(1,0),(1,1).
// Reads: ph0 af0+b0f (12), ph1 b1f (4), ph2 af1 (8), ph3 none.
// No manual lgkm waits: compiler emits per-use lgkmcnt so MFMA overlaps the
// tail of each LDS burst. Staging spread: ph0 buf^1.B1<-t+1, ph1 buf^1.A1<-t+1,
// ph2 buf.B0<-t+2, ph3 buf.A0<-t+2.
// Barriers: ONLY end-ph1 (WAR fence) and end-ph3 (boundary, after vmcnt(4)).
#define TILE(BUF, T, S01, S23, ENDW) do {                                                \
    /* phase 0 */                                                                        \
    READ_A(BUF, 0);                                                                      \
    READ_B(BUF, 0, b0f);                                                                 \
    if (S01) STAGE(((BUF) ^ 1) * 32768 + 3 * 8192, srcB1 + (size_t)((T) + 1) * 64);      \
    QUAD(0, 0, b0f);                                                                     \
    /* phase 1 */                                                                        \
    READ_B(BUF, 1, b1f);                                                                 \
    if (S01) STAGE(((BUF) ^ 1) * 32768 + 1 * 8192, srcA1 + (size_t)((T) + 1) * 64);      \
    QUAD(0, 1, b1f);                                                                     \
    BARF();   /* mid-tile WAR fence */                                                   \
    /* phase 2 */                                                                        \
    READ_A(BUF, 1);                                                                      \
    if (S23) STAGE((BUF) * 32768 + 2 * 8192, srcB0 + (size_t)((T) + 2) * 64);            \
    QUAD(1, 0, b0f);                                                                     \
    /* phase 3 (no reads; MFMA on resident regs) */                                      \
    if (S23) STAGE((BUF) * 32768 + 0 * 8192, srcA0 + (size_t)((T) + 2) * 64);            \
    QUAD(1, 1, b1f);                                                                     \
    if ((ENDW) == 4) VMW(4);                                                             \
    else if ((ENDW) == 0) VMW(0);                                                        \
    BARF();   /* tile boundary */                                                        \
} while (0)

__global__ __launch_bounds__(512, 2)
void gemm256_kernel(const bf16_t* __restrict__ A,
                    const bf16_t* __restrict__ B,
                    const float* __restrict__ bias,
                    float* __restrict__ C,
                    int M, int N, int K) {
    // 128 KiB: buf{0,1} x slots {A0,A1,B0,B1} x 8192 bf16 (128 rows x 64 cols)
    __shared__ bf16_t lds[65536];

    const int ntn = N / BN;
    const int nwg = gridDim.x;
    // bijective XCD swizzle (8 XCDs)
    const int q = nwg >> 3, r = nwg & 7;
    const int xcd = blockIdx.x & 7, lid = blockIdx.x >> 3;
    const int swz = (xcd < r ? xcd * (q + 1) : r * (q + 1) + (xcd - r) * q) + lid;
    const int tile_m = (swz / ntn) * BM;
    const int tile_n = (swz % ntn) * BN;

    const int tid = threadIdx.x;
    const int lane = tid & 63;
    const int wid = tid >> 6;
    const int wm = wid >> 2;   // 0..1: row half
    const int wn = wid & 3;    // 0..3: col quarter
    const int fr = lane & 15;
    const int hi = lane >> 4;
    const int fr7 = fr & 7;

    // inverse-swizzled global source column (bytes 4-6 ^= row bits 0-2; row=tid>>3)
    const int colsrc_e = ((((tid & 7) * 16) ^ ((tid & 56) << 1)) >> 1);
    const bf16_t* srcA0 = A + (size_t)(tile_m + (tid >> 3)) * K + colsrc_e;
    const bf16_t* srcA1 = srcA0 + (size_t)128 * K;
    const bf16_t* srcB0 = B + (size_t)(tile_n + (tid >> 3)) * K + colsrc_e;
    const bf16_t* srcB1 = srcB0 + (size_t)128 * K;

    bf16x8 af[4][2], b0f[2][2], b1f[2][2];
    f32x4 acc[8][4] = {};

    // prologue: tile0 fully + tile1's B0/A0; drain to 4 outstanding
    // (tile0 landed, tile1 B0/A0 in flight -> matches steady state).
    STAGE(16384, srcB0);               // buf0.B0 t0
    STAGE(0, srcA0);                   // buf0.A0 t0
    STAGE(24576, srcB1);               // buf0.B1 t0
    STAGE(8192, srcA1);                // buf0.A1 t0
    STAGE(32768 + 16384, srcB0 + 64);  // buf1.B0 t1
    STAGE(32768 + 0, srcA0 + 64);      // buf1.A0 t1
    VMW(4);
    BARF();

    const int npairs = K / 128;        // 2 K-tiles per iteration
    for (int i = 0; i < npairs - 1; ++i) {
        TILE(0, 2 * i, 1, 1, 4);
        TILE(1, 2 * i + 1, 1, 1, 4);
    }
    // tail: tile 2np-2 stages B1/A1(2np-1) only; drain all at its boundary
    TILE(0, 2 * npairs - 2, 1, 0, 0);
    TILE(1, 2 * npairs - 1, 0, 0, -1);

    // epilogue: C/D layout col=lane&15, row=(lane>>4)*4+reg
    float qb[4];
#pragma unroll
    for (int ng = 0; ng < 4; ++ng)
        qb[ng] = q16(bias[tile_n + wn * 64 + ng * 16 + fr]);
#pragma unroll
    for (int mg = 0; mg < 8; ++mg) {
        const int grow0 = tile_m + wm * 128 + mg * 16 + hi * 4;
#pragma unroll
        for (int ng = 0; ng < 4; ++ng) {
            const int gcol = tile_n + wn * 64 + ng * 16 + fr;
#pragma unroll
            for (int rr = 0; rr < 4; ++rr)
                C[(size_t)(grow0 + rr) * N + gcol] = acc[mg][ng][rr] + qb[ng];
        }
    }
}

extern "C" void kernel_launch(void* const* d_in, const int* in_sizes, int n_in,
                              void* d_out, int out_size, void* d_ws, size_t ws_size,
                              hipStream_t stream) {
    const float* inp   = (const float*)d_in[0];
    const float* shift = (const float*)d_in[1];
    const float* sign_ = (const float*)d_in[2];
    const float* bias  = (const float*)d_in[3];
    float* out = (float*)d_out;

    const int OUT_F = in_sizes[3];              // 4096
    const int IN_F  = in_sizes[1] / OUT_F;      // 4096
    const int Mrows = in_sizes[0] / IN_F;       // 4096

    bf16_t* Aq = (bf16_t*)d_ws;
    bf16_t* Wq = Aq + (size_t)Mrows * IN_F;     // (M*K + N*K)*2 = 67.2 MB of ws

    const int nA = Mrows * IN_F;                // == OUT_F * IN_F here

    convert_kernel<<<2048, 256, 0, stream>>>(inp, shift, sign_, Aq, Wq, nA >> 2);

    dim3 grid((Mrows / BM) * (OUT_F / BN));
    gemm256_kernel<<<grid, 512, 0, stream>>>(Aq, Wq, bias, out,
                                             Mrows, OUT_F, IN_F);
}